// Round 6
// baseline (55.441 us; speedup 1.0000x reference)
//
#include <hip/hip_runtime.h>

// Cox time-dependent loss, 2-dispatch pipeline.
// loss = -(sum ev*e) + sum_b histC[b]*log(inclE[b]),
// inclE = flipped prefix sum of per-bin sum of exp(r), B=4096 bins.
// K1: per-block LDS histograms (R3-proven 256x1024 config), partials packed
//     bf16(E)+u8(C) -> 3 MB instead of 6.
// K2: reduce + (last-block ticket) scan+dot+output in ONE dispatch --
//     removes one ~4.5us launch gap. Fence cost is tiny (16KB dirty), unlike
//     R4's grid.sync (flushed the whole 48MB stream, +45us).

constexpr int B = 4096;
constexpr float TMAX = 1000.0f;
constexpr int HIST_BLOCKS = 256;
constexpr int HIST_THREADS = 1024;
constexpr int RED_BLOCKS = 64;          // K2: each block reduces 64 bins

__device__ __forceinline__ int flip_bin(float t) {
    float x = t * ((float)B / TMAX);
    int b = (int)x;
    b = b < 0 ? 0 : (b > B - 1 ? B - 1 : b);
    return (B - 1) - b;                 // flipped: suffix-sum -> prefix-sum
}

__device__ __forceinline__ unsigned short f2bf(float f) {  // RNE f32->bf16
    unsigned u = __float_as_uint(f);
    u += 0x7FFFu + ((u >> 16) & 1u);
    return (unsigned short)(u >> 16);
}
__device__ __forceinline__ float bf2f(unsigned short h) {
    return __uint_as_float((unsigned)h << 16);
}

// K1: per-block LDS histograms (E = sum exp(r), C = event count) + sum(ev*e).
__global__ __launch_bounds__(HIST_THREADS)
void hist_kernel(const float4* __restrict__ risk4,
                 const float4* __restrict__ y4,      // pairs of (t,ev)
                 unsigned short* __restrict__ pE, unsigned char* __restrict__ pC,
                 float* __restrict__ seePartial, unsigned int* __restrict__ counter,
                 int n) {
    __shared__ float hE[B];
    __shared__ unsigned int hC[B];
    __shared__ float wsum[HIST_THREADS / 64];
    const int tid = threadIdx.x;
    if (blockIdx.x == 0 && tid == 0) *counter = 0u;   // reset K2's ticket
    for (int i = tid; i < B; i += HIST_THREADS) { hE[i] = 0.f; hC[i] = 0u; }
    __syncthreads();

    const int n4 = n >> 2;
    const int gsz = gridDim.x * blockDim.x;
    float see = 0.f;
    for (int i = blockIdx.x * blockDim.x + tid; i < n4; i += gsz) {
        float4 r  = risk4[i];
        float4 ya = y4[2 * i];          // (t0,ev0,t1,ev1)
        float4 yb = y4[2 * i + 1];      // (t2,ev2,t3,ev3)
        float e0 = __expf(r.x), e1 = __expf(r.y);
        float e2 = __expf(r.z), e3 = __expf(r.w);
        int b0 = flip_bin(ya.x), b1 = flip_bin(ya.z);
        int b2 = flip_bin(yb.x), b3 = flip_bin(yb.z);
        atomicAdd(&hE[b0], e0);
        atomicAdd(&hE[b1], e1);
        atomicAdd(&hE[b2], e2);
        atomicAdd(&hE[b3], e3);
        if (ya.y != 0.f) { atomicAdd(&hC[b0], 1u); see += e0; }
        if (ya.w != 0.f) { atomicAdd(&hC[b1], 1u); see += e1; }
        if (yb.y != 0.f) { atomicAdd(&hC[b2], 1u); see += e2; }
        if (yb.w != 0.f) { atomicAdd(&hC[b3], 1u); see += e3; }
    }
    if (blockIdx.x == 0 && tid < (n & 3)) {           // scalar tail (safety)
        int i = (n4 << 2) + tid;
        const float* risk = (const float*)risk4;
        const float* yraw = (const float*)y4;
        float e = __expf(risk[i]);
        float t = yraw[2 * i], ev = yraw[2 * i + 1];
        int b = flip_bin(t);
        atomicAdd(&hE[b], e);
        if (ev != 0.f) { atomicAdd(&hC[b], 1u); see += e; }
    }

    #pragma unroll
    for (int off = 32; off > 0; off >>= 1) see += __shfl_down(see, off, 64);
    if ((tid & 63) == 0) wsum[tid >> 6] = see;
    __syncthreads();
    if (tid == 0) {
        float s = 0.f;
        #pragma unroll
        for (int w = 0; w < HIST_THREADS / 64; ++w) s += wsum[w];
        seePartial[blockIdx.x] = s;
    }

    unsigned short* oE = pE + (size_t)blockIdx.x * B;
    unsigned char*  oC = pC + (size_t)blockIdx.x * B;
    for (int i = tid; i < B; i += HIST_THREADS) {
        oE[i] = f2bf(hE[i]);            // per-bin partial ~O(10): bf16 fine
        oC[i] = (unsigned char)hC[i];   // lambda~1/bin: never near 255
    }
}

// K2: reduce 256 partial copies -> histE/histC; last-arriving block does
// scan + dot + output. 64 blocks x 1024 threads (64 bins x 16 copy-lanes).
__global__ __launch_bounds__(1024)
void reduce_scan_dot_kernel(const unsigned short* __restrict__ pE,
                            const unsigned char* __restrict__ pC,
                            float* __restrict__ histE, float* __restrict__ histC,
                            const float* __restrict__ seePartial,
                            unsigned int* __restrict__ counter,
                            float* __restrict__ out) {
    __shared__ float smE[1024];
    __shared__ float smC[1024];
    __shared__ double sd[1024];
    __shared__ int lastFlag;
    const int tid = threadIdx.x;
    const int binOff = tid & 63;
    const int cl = tid >> 6;                 // 0..15 copy-lanes
    const int base = blockIdx.x * 64;

    float sE = 0.f, sC = 0.f;
    #pragma unroll
    for (int k = 0; k < HIST_BLOCKS / 16; ++k) {
        int c = cl * (HIST_BLOCKS / 16) + k;
        size_t idx = (size_t)c * B + base + binOff;
        sE += bf2f(pE[idx]);
        sC += (float)pC[idx];
    }
    smE[tid] = sE;
    smC[tid] = sC;
    __syncthreads();
    #pragma unroll
    for (int off = 8; off >= 1; off >>= 1) {
        if (cl < off) {
            smE[tid] += smE[tid + off * 64];
            smC[tid] += smC[tid + off * 64];
        }
        __syncthreads();
    }
    if (tid < 64) {
        histE[base + tid] = smE[tid];
        histC[base + tid] = smC[tid];
    }

    // ---- decoupled completion: last block finishes the job ----
    __threadfence();                         // release histE/histC
    if (tid == 0)
        lastFlag = (atomicAdd(counter, 1u) == (unsigned)(RED_BLOCKS - 1));
    __syncthreads();
    if (!lastFlag) return;
    __threadfence();                         // acquire all blocks' writes

    // inclusive scan of histE (1024 threads x 4 bins), reuse smE
    float4 a = ((const float4*)histE)[tid];
    float s0 = a.x;
    float s1 = s0 + a.y;
    float s2 = s1 + a.z;
    float s3 = s2 + a.w;
    smE[tid] = s3;
    __syncthreads();
    for (int off = 1; off < 1024; off <<= 1) {
        float t_ = (tid >= off) ? smE[tid - off] : 0.f;
        __syncthreads();
        smE[tid] += t_;
        __syncthreads();
    }
    float excl = smE[tid] - s3;
    float4 c = ((const float4*)histC)[tid];
    float p = c.x * __logf(fmaxf(excl + s0, 1e-35f))
            + c.y * __logf(fmaxf(excl + s1, 1e-35f))
            + c.z * __logf(fmaxf(excl + s2, 1e-35f))
            + c.w * __logf(fmaxf(excl + s3, 1e-35f));

    double v = (double)p;
    if (tid < HIST_BLOCKS) v -= (double)seePartial[tid];
    sd[tid] = v;
    __syncthreads();
    #pragma unroll
    for (int off = 512; off > 0; off >>= 1) {
        if (tid < off) sd[tid] += sd[tid + off];
        __syncthreads();
    }
    if (tid == 0) out[0] = (float)sd[0];
}

extern "C" void kernel_launch(void* const* d_in, const int* in_sizes, int n_in,
                              void* d_out, int out_size, void* d_ws, size_t ws_size,
                              hipStream_t stream) {
    const float4* risk4 = (const float4*)d_in[0];
    const float4* y4    = (const float4*)d_in[1];
    const int n = in_sizes[0];

    unsigned short* pE   = (unsigned short*)d_ws;                           // 2 MB
    unsigned char*  pC   = (unsigned char*)(pE + (size_t)HIST_BLOCKS * B);  // 1 MB
    float* histE         = (float*)(pC + (size_t)HIST_BLOCKS * B);
    float* histC         = histE + B;
    float* seePartial    = histC + B;
    unsigned int* counter = (unsigned int*)(seePartial + HIST_BLOCKS);
    float* out           = (float*)d_out;

    hist_kernel<<<HIST_BLOCKS, HIST_THREADS, 0, stream>>>(
        risk4, y4, pE, pC, seePartial, counter, n);
    reduce_scan_dot_kernel<<<RED_BLOCKS, 1024, 0, stream>>>(
        pE, pC, histE, histC, seePartial, counter, out);
}

// Round 8
// 42.359 us; speedup vs baseline: 1.3088x; 1.3088x over previous
//
#include <hip/hip_runtime.h>

// Cox time-dependent loss, 3-kernel pipeline (R3-proven structure).
// loss = -(sum ev*e) + sum_b histC[b]*log(inclE[b]),
// inclE = flipped prefix sum of per-bin sum of exp(r), B=4096 bins.
// R4/R6 lessons: grid.sync and threadfence-ticket patterns cost MORE than
// launch gaps on 8-XCD MI355X -> keep 3 plain dispatches.
// R8 = R7 with the nontemporal builtin fed a native ext_vector_type pointer
// (HIP_vector_type<float,4> is rejected by the builtin).

constexpr int B = 4096;
constexpr float TMAX = 1000.0f;
constexpr int HIST_BLOCKS = 256;
constexpr int HIST_THREADS = 1024;

typedef float f4 __attribute__((ext_vector_type(4)));   // native vec for builtins

__device__ __forceinline__ int flip_bin(float t) {
    float x = t * ((float)B / TMAX);
    int b = (int)x;
    b = b < 0 ? 0 : (b > B - 1 ? B - 1 : b);
    return (B - 1) - b;                 // flipped: suffix-sum -> prefix-sum
}

// Pass 1: per-block LDS histograms (E = sum exp(r), C = event count) + sum(ev*e).
__global__ __launch_bounds__(HIST_THREADS)
void hist_kernel(const f4* __restrict__ risk4,
                 const f4* __restrict__ y4,          // pairs of (t,ev)
                 float* __restrict__ pE, unsigned short* __restrict__ pC,
                 float* __restrict__ seePartial, int n) {
    __shared__ float hE[B];
    __shared__ unsigned int hC[B];
    __shared__ float wsum[HIST_THREADS / 64];
    const int tid = threadIdx.x;
    for (int i = tid; i < B; i += HIST_THREADS) { hE[i] = 0.f; hC[i] = 0u; }
    __syncthreads();

    const int n4 = n >> 2;
    const int gsz = gridDim.x * blockDim.x;
    float see = 0.f;
    for (int i = blockIdx.x * blockDim.x + tid; i < n4; i += gsz) {
        f4 r  = __builtin_nontemporal_load(&risk4[i]);
        f4 ya = __builtin_nontemporal_load(&y4[2 * i]);      // (t0,ev0,t1,ev1)
        f4 yb = __builtin_nontemporal_load(&y4[2 * i + 1]);  // (t2,ev2,t3,ev3)
        float e0 = __expf(r.x), e1 = __expf(r.y);
        float e2 = __expf(r.z), e3 = __expf(r.w);
        int b0 = flip_bin(ya.x), b1 = flip_bin(ya.z);
        int b2 = flip_bin(yb.x), b3 = flip_bin(yb.z);
        atomicAdd(&hE[b0], e0);
        atomicAdd(&hE[b1], e1);
        atomicAdd(&hE[b2], e2);
        atomicAdd(&hE[b3], e3);
        if (ya.y != 0.f) { atomicAdd(&hC[b0], 1u); see += e0; }
        if (ya.w != 0.f) { atomicAdd(&hC[b1], 1u); see += e1; }
        if (yb.y != 0.f) { atomicAdd(&hC[b2], 1u); see += e2; }
        if (yb.w != 0.f) { atomicAdd(&hC[b3], 1u); see += e3; }
    }
    // scalar tail (n % 4) — n=4194304 is divisible, kept for safety
    if (blockIdx.x == 0 && tid < (n & 3)) {
        int i = (n4 << 2) + tid;
        const float* risk = (const float*)risk4;
        const float* yraw = (const float*)y4;
        float e = __expf(risk[i]);
        float t = yraw[2 * i], ev = yraw[2 * i + 1];
        int b = flip_bin(t);
        atomicAdd(&hE[b], e);
        if (ev != 0.f) { atomicAdd(&hC[b], 1u); see += e; }
    }

    #pragma unroll
    for (int off = 32; off > 0; off >>= 1) see += __shfl_down(see, off, 64);
    if ((tid & 63) == 0) wsum[tid >> 6] = see;
    __syncthreads();
    if (tid == 0) {
        float s = 0.f;
        #pragma unroll
        for (int w = 0; w < HIST_THREADS / 64; ++w) s += wsum[w];
        seePartial[blockIdx.x] = s;
    }

    float* oE = pE + (size_t)blockIdx.x * B;
    unsigned short* oC = pC + (size_t)blockIdx.x * B;
    for (int i = tid; i < B; i += HIST_THREADS) {
        oE[i] = hE[i];
        oC[i] = (unsigned short)hC[i];
    }
}

// Pass 2: reduce 256 partial copies -> histE[B], histC[B] (as float).
__global__ __launch_bounds__(256)
void reduce_hist_kernel(const float* __restrict__ pE,
                        const unsigned short* __restrict__ pC,
                        float* __restrict__ histE, float* __restrict__ histC) {
    const int binBase = blockIdx.x * 16;
    const int binOff = threadIdx.x & 15;
    const int lane = threadIdx.x >> 4;      // 0..15
    const int bin = binBase + binOff;

    float sE = 0.f, sC = 0.f;
    for (int c = lane; c < HIST_BLOCKS; c += 16) {
        sE += pE[(size_t)c * B + bin];
        sC += (float)pC[(size_t)c * B + bin];
    }
    __shared__ float smE[256], smC[256];
    smE[threadIdx.x] = sE;
    smC[threadIdx.x] = sC;
    __syncthreads();
    if (threadIdx.x < 16) {
        float aE = 0.f, aC = 0.f;
        #pragma unroll
        for (int l = 0; l < 16; ++l) {
            aE += smE[l * 16 + threadIdx.x];
            aC += smC[l * 16 + threadIdx.x];
        }
        histE[binBase + threadIdx.x] = aE;
        histC[binBase + threadIdx.x] = aC;
    }
}

// Pass 3 (1 block, 1024 threads): shuffle-scan histE, dot with histC*log, minus see.
__global__ __launch_bounds__(1024)
void scan_dot_kernel(const float* __restrict__ histE,
                     const float* __restrict__ histC,
                     const float* __restrict__ seePartial,
                     float* __restrict__ out) {
    __shared__ float waveSum[16];
    __shared__ double dsum[16];
    const int tid = threadIdx.x;
    const int lane = tid & 63;
    const int wid = tid >> 6;               // 0..15

    float4 a = ((const float4*)histE)[tid];
    float s0 = a.x;
    float s1 = s0 + a.y;
    float s2 = s1 + a.z;
    float s3 = s2 + a.w;

    // intra-wave inclusive scan of per-thread sums (6 shfl steps)
    float v = s3;
    #pragma unroll
    for (int off = 1; off < 64; off <<= 1) {
        float t_ = __shfl_up(v, off, 64);
        if (lane >= off) v += t_;
    }
    if (lane == 63) waveSum[wid] = v;
    __syncthreads();
    // wave 0 scans the 16 wave totals
    if (wid == 0) {
        float w = (lane < 16) ? waveSum[lane] : 0.f;
        #pragma unroll
        for (int off = 1; off < 16; off <<= 1) {
            float t_ = __shfl_up(w, off, 64);
            if (lane >= off) w += t_;
        }
        if (lane < 16) waveSum[lane] = w;   // inclusive wave prefix
    }
    __syncthreads();
    float waveExcl = (wid == 0) ? 0.f : waveSum[wid - 1];
    float excl = waveExcl + v - s3;         // exclusive prefix for this thread

    float4 c = ((const float4*)histC)[tid];
    float p = c.x * __logf(fmaxf(excl + s0, 1e-35f))
            + c.y * __logf(fmaxf(excl + s1, 1e-35f))
            + c.z * __logf(fmaxf(excl + s2, 1e-35f))
            + c.w * __logf(fmaxf(excl + s3, 1e-35f));

    double d = (double)p;
    if (tid < HIST_BLOCKS) d -= (double)seePartial[tid];
    // intra-wave double reduction
    #pragma unroll
    for (int off = 32; off > 0; off >>= 1) d += __shfl_down(d, off, 64);
    if (lane == 0) dsum[wid] = d;
    __syncthreads();
    if (tid == 0) {
        double s = 0.0;
        #pragma unroll
        for (int w = 0; w < 16; ++w) s += dsum[w];
        out[0] = (float)s;
    }
}

extern "C" void kernel_launch(void* const* d_in, const int* in_sizes, int n_in,
                              void* d_out, int out_size, void* d_ws, size_t ws_size,
                              hipStream_t stream) {
    const f4* risk4 = (const f4*)d_in[0];
    const f4* y4    = (const f4*)d_in[1];
    const int n = in_sizes[0];

    float* pE            = (float*)d_ws;                                    // 256*4096 f = 4MB
    unsigned short* pC   = (unsigned short*)(pE + (size_t)HIST_BLOCKS * B); // 2MB
    float* histE         = (float*)(pC + (size_t)HIST_BLOCKS * B);          // 4096 f
    float* histC         = histE + B;                                       // 4096 f
    float* seePartial    = histC + B;                                       // 256 f

    hist_kernel<<<HIST_BLOCKS, HIST_THREADS, 0, stream>>>(risk4, y4, pE, pC, seePartial, n);
    reduce_hist_kernel<<<B / 16, 256, 0, stream>>>(pE, pC, histE, histC);
    scan_dot_kernel<<<1, 1024, 0, stream>>>(histE, histC, seePartial, (float*)d_out);
}